// Round 11
// baseline (205.740 us; speedup 1.0000x reference)
//
#include <hip/hip_runtime.h>

// SparseMLP (grouped GEMM MoE): out = gelu_tanh(x @ w1^T) @ w2, per expert.
// E=64, CAP=64, H=1024, F=2048, fp32 in/out. HBM-bound: ~1.09 GB moved,
// roofline ~160-173us at the 6.3-6.85 TB/s measured ceilings.
// R11: 3-deep prefetch done RIGHT (R7 failed via rule #20 runtime-select ->
// scratch): statically-named ping-pong register sets (ra0/ra1, rb0/rb1),
// K-loop unrolled x2 so every set reference is compile-time. The set consumed
// by writeT was issued TWO loop bodies earlier (~full HBM latency) and ~2
// tiles of loads stay in flight across each barrier -> smooth DRAM demand.
// Pass1: BM=64 BN=64 BK=128 (R10). Pass2: BK=64 (R6). nt w-loads (R5),
// T1 XCD swizzle, T2 LDS XOR swizzle, T4 counted-wait barriers.

typedef __attribute__((ext_vector_type(8))) short short8;    // 8 bf16 = 4 VGPR
typedef __attribute__((ext_vector_type(4))) float f32x4;     // MFMA acc / ld
typedef __attribute__((ext_vector_type(8))) unsigned short ushort8;

#define NE   64
#define CAPT 64
#define HD   1024
#define FD   2048

// fp32 -> bf16 round-to-nearest-even
__device__ __forceinline__ unsigned short f2bf(float f) {
  union { float f; unsigned u; } v; v.f = f;
  unsigned r = v.u + 0x7FFFu + ((v.u >> 16) & 1u);
  return (unsigned short)(r >> 16);
}

// gelu_tanh(v) = v * sigmoid(2*0.79788456*(v + 0.044715 v^3))  (exact rewrite)
__device__ __forceinline__ float gelu_t(float v) {
  float u = 1.5957691216057308f * (v + 0.044715f * v * v * v);
  return v / (1.0f + __expf(-u));
}

// XOR swizzle (T2) for a [rows][64]-bf16 tile (row stride 128B): pass 2.
__device__ __forceinline__ int swz(int row, int kbyte) {
  return row * 128 + (kbyte ^ ((row & 7) << 4));
}
// XOR swizzle for a [rows][128]-bf16 tile (row stride 256B): pass 1 (BK=128).
__device__ __forceinline__ int swz2(int row, int kbyte) {
  return row * 256 + (kbyte ^ ((row & 7) << 4));
}

__device__ __forceinline__ void cvt_wr4(unsigned char* dst, f32x4 v) {
  uint2 p;
  p.x = (unsigned)f2bf(v.x) | ((unsigned)f2bf(v.y) << 16);
  p.y = (unsigned)f2bf(v.z) | ((unsigned)f2bf(v.w) << 16);
  *(uint2*)dst = p;   // ds_write_b64
}

// Raw barrier with LDS-only drain (T4): outstanding GLOBAL loads stay in
// flight across the barrier; register deps produce counted vmcnt waits.
__device__ __forceinline__ void tile_barrier() {
  asm volatile("s_waitcnt lgkmcnt(0)" ::: "memory");
  __builtin_amdgcn_s_barrier();
  __builtin_amdgcn_sched_barrier(0);
}

// Bijective XCD swizzle (T1): same-expert blocks share an L2.
__device__ __forceinline__ int xcd_swz(int bid, int grid) {
  return (bid & 7) * (grid >> 3) + (bid >> 3);
}

// ---------------------------------------------------------------- pass 1 ---
// C1[64,2048] = x_e[64,1024] @ w1_e[2048,1024]^T  (NT: both K-contiguous)
// grid = E*(F/64)=2048; tile BM=64 BN=64 BK=128; 8 waves (2x4), wave 32x16.
#define P1_TSZ (64 * 256)          // one [64][128]-bf16 buffer, bytes
__global__ __launch_bounds__(512, 4)
void moe_pass1(const float* __restrict__ x, const float* __restrict__ w1,
               unsigned short* __restrict__ hb) {
  __shared__ __align__(16) unsigned char sA[2 * P1_TSZ];   // 32 KB
  __shared__ __align__(16) unsigned char sB[2 * P1_TSZ];   // 32 KB
  const int bid = xcd_swz(blockIdx.x, NE * 32);
  const int e = bid >> 5, nb = bid & 31;
  const int t = threadIdx.x, lane = t & 63, wid = t >> 6;
  const int wm = wid >> 2, wn = wid & 3;
  const int lr = lane & 15, lk16 = (lane >> 4) * 16;

  const float* xg  = x  + (size_t)e * CAPT * HD;
  const float* w1g = w1 + ((size_t)e * FD + (size_t)nb * 64) * HD;

  f32x4 acc[2] = {};

  // 3-deep ping-pong sets, statically named (rule #20: no runtime selects).
  f32x4 ra0[4], ra1[4], rb0[4], rb1[4];
  auto loadA = [&](f32x4 (&ra)[4], int k0) {
    #pragma unroll
    for (int i = 0; i < 4; ++i) {
      int u = t + i * 512;
      ra[i] = *(const f32x4*)(xg + (u >> 5) * HD + k0 + (u & 31) * 4);
    }
  };
  auto loadB = [&](f32x4 (&rb)[4], int k0) {
    #pragma unroll
    for (int i = 0; i < 4; ++i) {
      int u = t + i * 512;
      rb[i] = __builtin_nontemporal_load(                    // single-use stream
          (const f32x4*)(w1g + (u >> 5) * HD + k0 + (u & 31) * 4));
    }
  };
  auto writeT = [&](unsigned char* a, unsigned char* b,
                    f32x4 (&ra)[4], f32x4 (&rb)[4]) {
    #pragma unroll
    for (int i = 0; i < 4; ++i) {
      int u = t + i * 512;
      cvt_wr4(a + swz2(u >> 5, (u & 31) * 8), ra[i]);
    }
    #pragma unroll
    for (int i = 0; i < 4; ++i) {
      int u = t + i * 512;
      cvt_wr4(b + swz2(u >> 5, (u & 31) * 8), rb[i]);
    }
  };

  const int NK = HD / 128;                                   // 8 K-steps
  // prologue: tile0 staged via set0; tile1 -> set1; tile2 -> set0 (3-deep)
  loadA(ra0, 0);   loadB(rb0, 0);
  writeT(sA, sB, ra0, rb0);
  loadA(ra1, 128); loadB(rb1, 128);
  loadA(ra0, 256); loadB(rb0, 256);
  tile_barrier();

  int cur = 0;
  // iter ks: stage tile ks+1 (parity (ks+1)&1), refill same set w/ tile ks+3
  auto step = [&](int ks, f32x4 (&raS)[4], f32x4 (&rbS)[4]) {
    unsigned char* cA = sA + cur * P1_TSZ;
    unsigned char* cB = sB + cur * P1_TSZ;
    if (ks + 1 < NK) writeT(sA + (cur ^ 1) * P1_TSZ, sB + (cur ^ 1) * P1_TSZ,
                            raS, rbS);
    if (ks + 3 < NK) { loadA(raS, (ks + 3) * 128); loadB(rbS, (ks + 3) * 128); }

    #pragma unroll
    for (int kk = 0; kk < 4; ++kk) {                         // K=128 = 4x32
      short8 af0 = *(const short8*)(cA + swz2(wm * 32 + lr,      kk * 64 + lk16));
      short8 af1 = *(const short8*)(cA + swz2(wm * 32 + 16 + lr, kk * 64 + lk16));
      short8 bfr = *(const short8*)(cB + swz2(wn * 16 + lr,      kk * 64 + lk16));
      acc[0] = __builtin_amdgcn_mfma_f32_16x16x32_bf16(af0, bfr, acc[0], 0, 0, 0);
      acc[1] = __builtin_amdgcn_mfma_f32_16x16x32_bf16(af1, bfr, acc[1], 0, 0, 0);
    }
    tile_barrier();
    cur ^= 1;
  };
  #pragma unroll 1
  for (int ks = 0; ks < NK; ks += 2) {
    step(ks,     ra1, rb1);    // consumes odd tile ks+1
    step(ks + 1, ra0, rb0);    // consumes even tile ks+2
  }

  // epilogue: gelu, cvt bf16, store h. C/D map: col=lane&15, row=(lane>>4)*4+j
  unsigned short* hp = hb + (size_t)e * CAPT * FD + nb * 64;
  #pragma unroll
  for (int fm = 0; fm < 2; ++fm)
    #pragma unroll
    for (int j = 0; j < 4; ++j) {
      int m = wm * 32 + fm * 16 + (lane >> 4) * 4 + j;
      int f = wn * 16 + lr;
      hp[(size_t)m * FD + f] = f2bf(gelu_t(acc[fm][j]));
    }
}

#define A_SZ (64 * 128)
#define B_SZ (128 * 128)

// ---------------------------------------------------------------- pass 2 ---
// C2[64,1024] = h_e[64,2048](bf16) @ w2_e[2048,1024]  (NN: w2 transposed at
// stage time into LDS [n][k]). R6 body + 3-deep static ping-pong staging.
__global__ __launch_bounds__(512, 4)
void moe_pass2(const unsigned short* __restrict__ hb, const float* __restrict__ w2,
               float* __restrict__ out) {
  __shared__ __align__(16) unsigned char sA[2 * A_SZ];
  __shared__ __align__(16) unsigned char sB[2 * B_SZ];
  const int bid = xcd_swz(blockIdx.x, NE * 8);
  const int e = bid >> 3, nb = bid & 7;
  const int t = threadIdx.x, lane = t & 63, wid = t >> 6;
  const int wm = wid >> 2, wn = wid & 3;
  const int lr = lane & 15, lkb = (lane >> 4) * 16;

  const unsigned short* hg = hb + (size_t)e * CAPT * FD;
  const float* w2g = w2 + (size_t)e * FD * HD + nb * 128;

  f32x4 acc[2][2] = {};

  const int ar = t >> 3, ac = t & 7;     // A: 512 units of 8 bf16, 1/thread
  const int bn = t & 127, bkg = t >> 7;  // B: lane owns col n, k-group of 16

  ushort8 rav0, rav1;
  float rbv0[16], rbv1[16];
  auto loadA = [&](ushort8& rav, int f0) {
    rav = *(const ushort8*)(hg + (size_t)ar * FD + f0 + ac * 8);   // L2/L3-warm
  };
  auto loadB = [&](float (&rbv)[16], int f0) {
    #pragma unroll
    for (int i = 0; i < 4; ++i)
      #pragma unroll
      for (int j = 0; j < 4; ++j)
        rbv[i * 4 + j] = __builtin_nontemporal_load(                // stream
            w2g + (size_t)(f0 + bkg * 16 + i * 4 + j) * HD + bn);
  };
  auto writeT = [&](unsigned char* a, unsigned char* b,
                    ushort8& rav, float (&rbv)[16]) {
    *(ushort8*)(a + swz(ar, ac * 16)) = rav;           // ds_write_b128
    #pragma unroll
    for (int i = 0; i < 4; ++i) {                      // transposed b64 writes
      uint2 p;
      p.x = (unsigned)f2bf(rbv[i * 4 + 0]) | ((unsigned)f2bf(rbv[i * 4 + 1]) << 16);
      p.y = (unsigned)f2bf(rbv[i * 4 + 2]) | ((unsigned)f2bf(rbv[i * 4 + 3]) << 16);
      *(uint2*)(b + swz(bn, (bkg * 16 + i * 4) * 2)) = p;
    }
  };

  const int NK = FD / 64;                                   // 32 K-steps
  loadA(rav0, 0);   loadB(rbv0, 0);
  writeT(sA, sB, rav0, rbv0);
  loadA(rav1, 64);  loadB(rbv1, 64);
  loadA(rav0, 128); loadB(rbv0, 128);
  tile_barrier();

  int cur = 0;
  auto step = [&](int ks, ushort8& ravS, float (&rbvS)[16]) {
    unsigned char* cA = sA + cur * A_SZ;
    unsigned char* cB = sB + cur * B_SZ;
    if (ks + 1 < NK) writeT(sA + (cur ^ 1) * A_SZ, sB + (cur ^ 1) * B_SZ,
                            ravS, rbvS);
    if (ks + 3 < NK) { loadA(ravS, (ks + 3) * 64); loadB(rbvS, (ks + 3) * 64); }

    short8 af[2][2], bf[2][2];
    #pragma unroll
    for (int fm = 0; fm < 2; ++fm)
      #pragma unroll
      for (int kk = 0; kk < 2; ++kk)
        af[fm][kk] = *(const short8*)(cA + swz(wm * 32 + fm * 16 + lr, kk * 64 + lkb));
    #pragma unroll
    for (int fn = 0; fn < 2; ++fn)
      #pragma unroll
      for (int kk = 0; kk < 2; ++kk)
        bf[fn][kk] = *(const short8*)(cB + swz(wn * 32 + fn * 16 + lr, kk * 64 + lkb));
    #pragma unroll
    for (int fm = 0; fm < 2; ++fm)
      #pragma unroll
      for (int fn = 0; fn < 2; ++fn) {
        acc[fm][fn] = __builtin_amdgcn_mfma_f32_16x16x32_bf16(af[fm][0], bf[fn][0], acc[fm][fn], 0, 0, 0);
        acc[fm][fn] = __builtin_amdgcn_mfma_f32_16x16x32_bf16(af[fm][1], bf[fn][1], acc[fm][fn], 0, 0, 0);
      }
    tile_barrier();
    cur ^= 1;
  };
  #pragma unroll 1
  for (int ks = 0; ks < NK; ks += 2) {
    step(ks,     rav1, rbv1);
    step(ks + 1, rav0, rbv0);
  }

  float* op = out + (size_t)e * CAPT * HD + nb * 128;
  #pragma unroll
  for (int fm = 0; fm < 2; ++fm)
    #pragma unroll
    for (int fn = 0; fn < 2; ++fn)
      #pragma unroll
      for (int j = 0; j < 4; ++j) {
        int m = wm * 32 + fm * 16 + (lane >> 4) * 4 + j;
        int n = wn * 32 + fn * 16 + lr;
        __builtin_nontemporal_store(acc[fm][fn][j], op + (size_t)m * HD + n);
      }
}

extern "C" void kernel_launch(void* const* d_in, const int* in_sizes, int n_in,
                              void* d_out, int out_size, void* d_ws, size_t ws_size,
                              hipStream_t stream) {
  const float* x  = (const float*)d_in[0];
  const float* w1 = (const float*)d_in[1];
  const float* w2 = (const float*)d_in[2];
  float* out = (float*)d_out;
  unsigned short* hb = (unsigned short*)d_ws;   // h: E*CAP*F bf16 = 16.78 MB
  (void)in_sizes; (void)n_in; (void)out_size; (void)ws_size;

  moe_pass1<<<dim3(NE * (FD / 64)), dim3(512), 0, stream>>>(x, w1, hb);
  moe_pass2<<<dim3(NE * (HD / 128)), dim3(512), 0, stream>>>(hb, w2, out);
}